// Round 7
// baseline (156.264 us; speedup 1.0000x reference)
//
#include <hip/hip_runtime.h>
#include <stdint.h>

// ---------------------------------------------------------------------------
// SlidingWindowAttention: B=2, N=2048, C=1024, H=16, Dh=64, window=512 (half=256)
// fp16 MFMA pipeline (4 dispatches) — R16 configuration:
//   prep: x->fp16, W_qkv^T, W_proj^T
//   GEMM1: 256x192, 4-phase/K-tile (m-quarters), counted vmcnt(7) (T4),
//     A 3-buf / B 2-buf (144 KiB LDS), grid 16x16=256 blocks (100% CU),
//     per phase: {4 ds_reads (+6 bf in P0) || stage || barrier || 12-MFMA
//     setprio cluster} — m196/m201 fine-interleave on top of R15's counted
//     schedule. lgkmcnt(0) BEFORE each barrier (collective read-completion
//     makes same-buffer B restage race-free).
//   attn v5 (R11 exact): 32x32 MFMA, 128q x 8 waves, K/V dbuf, P exchanged
//     in-register via __shfl_xor(.,32), setprio clusters
//   GEMM2 128x64 BK=64 (m97-structure): out = O2 @ Wpt^T + bias (fp32)
// Ladder: R14 (4-phase drain0, 2-buf, 75% grid) 44.4us/21% util ->
// R15 (2-phase counted, A3B2, 100% grid) ~27us -> R16 adds fine phases.
// Negative results (do NOT retry): R7 1-barrier dbuf BK=32 (+4.6us);
// R9 32x32x16 GEMM MFMA (+2.4us); R5 256q attn tiles (+8us); R10 raw-asm
// v_permlane32_swap (WRONG RESULTS); R12 attn counted-vmcnt 4-buf +
// sched_barrier fences (+7.4us); R13 __launch_bounds__(512,2) on 256² GEMM
// (VGPR cap 128 < acc -> spill); R14 drain0-per-tile (T3 gain IS T4, m218).
// Pre-commit: if R16 total > 153.2, revert gemm8p loop to R15 2-phase.
// ---------------------------------------------------------------------------

typedef _Float16 f16x8 __attribute__((ext_vector_type(8)));
typedef _Float16 f16x4 __attribute__((ext_vector_type(4)));
typedef __fp16   fp16x2n __attribute__((ext_vector_type(2)));
typedef float    f32x2 __attribute__((ext_vector_type(2)));
typedef float    f32x4 __attribute__((ext_vector_type(4)));
typedef float    f32x16 __attribute__((ext_vector_type(16)));

#define MFMA16(a, b, c) __builtin_amdgcn_mfma_f32_16x16x32_f16((a), (b), (c), 0, 0, 0)
#define MFMA32(a, b, c) __builtin_amdgcn_mfma_f32_32x32x16_f16((a), (b), (c), 0, 0, 0)

__device__ __forceinline__ void gload16(const void* g, void* l) {
  __builtin_amdgcn_global_load_lds(
      (const __attribute__((address_space(1))) void*)g,
      (__attribute__((address_space(3))) void*)l, 16, 0, 0);
}

__device__ __forceinline__ unsigned pk2(float a, float b) {
  fp16x2n t = __builtin_amdgcn_cvt_pkrtz(a, b);
  return __builtin_bit_cast(unsigned, t);
}

// -------------------------- fused prep -------------------------------------
__global__ __launch_bounds__(256) void prep(const float* __restrict__ x,
                                            const float* __restrict__ wqkv,
                                            const float* __restrict__ wproj,
                                            _Float16* __restrict__ Xb,
                                            _Float16* __restrict__ Wqt,
                                            _Float16* __restrict__ Wpt) {
  __shared__ float t[64][65];
  const int id = blockIdx.x, tid = threadIdx.x;
  if (id < 4096) {
    int i = (id * 256 + tid) * 4;
    float4 v = *(const float4*)(x + i);
    f16x4 h;
    h[0] = (_Float16)v.x; h[1] = (_Float16)v.y;
    h[2] = (_Float16)v.z; h[3] = (_Float16)v.w;
    *(f16x4*)(Xb + i) = h;
    return;
  }
  const float* in; _Float16* out; int N, bx, by;
  if (id < 4864) { int tt = id - 4096; in = wqkv; out = Wqt; N = 3072; bx = tt % 48; by = tt / 48; }
  else           { int tt = id - 4864; in = wproj; out = Wpt; N = 1024; bx = tt & 15; by = tt >> 4; }
  const int n0 = bx * 64, k0 = by * 64;
  {
    int j = tid & 63;
#pragma unroll
    for (int p = 0; p < 16; p++) {
      int i = p * 4 + (tid >> 6);
      t[i][j] = in[(size_t)(k0 + i) * N + n0 + j];
    }
  }
  __syncthreads();
  {
    int i = tid & 63;
#pragma unroll
    for (int p = 0; p < 16; p++) {
      int j = p * 4 + (tid >> 6);
      out[(size_t)(n0 + j) * 1024 + k0 + i] = (_Float16)t[i][j];
    }
  }
}

// -------------------------- GEMM1: 256x192 4-phase counted (R16) -----------
// C = A[4096][1024] @ Bt[3072][1024]^T. 512 thr = 8 waves (2M x 4N); per-wave
// output 128x48 = acc[8][3] f32x4 (96 AGPR). BK=64, 16 K-tiles.
// LDS: A 3 buffers x 32KB (rot-3: A(t) in Ab[t%3]) at smem+0;
//      B 2 buffers x 24KB (B(t) in Bb[t&1]) at smem+98304. Total 144 KiB.
// Rows 128B = 8x16B chunks XOR-swizzled slot = chunk ^ (row&7) (T2).
// Per K-tile t, 4 phases by m-quarter q (rows wm*128 + q*32 .. +31):
//   Pq: ds_read aq(4: 2 m-frags x 2 ks)  [+ bf(6: all 3 n-frags) in P0;
//       bf register-held for the whole tile]
//       P0 also stages A(t+2) [4 gloads]; P1 stages B(t+2) [3 gloads]
//       lgkmcnt(0); s_barrier   <- all waves' reads certified complete
//       setprio(1); 12 MFMA -> acc[2q..2q+1][0..2]; setprio(0)
//   tile boundary: vmcnt(7) (t<=13) / vmcnt(0) (t==14) ; s_barrier
//     (keeps this tile's 7 stage loads in flight — T4, never drain mid-loop;
//      awaited loads were issued a full tile (~4 phases) earlier)
// WAR audit: A-stage(t) hits Ab[(t-1)%3], whose last reads completed before
// tile t-1's P3 lgkm+barrier. B-stage(t) at P1 hits Bb[t&1] = buffer whose
// bf reads completed before P0's barrier. Prologue stages A0,B0,A1,B1
// (14 loads), vmcnt(7) leaves A1,B1 flying; raw s_barrier (NOT __syncthreads
// — that would drain vmcnt(0)).
__global__ __launch_bounds__(512) void gemm8p(const _Float16* __restrict__ A,
                                              const _Float16* __restrict__ Bt,
                                              _Float16* __restrict__ oh,
                                              _Float16* __restrict__ vt) {
  __shared__ __align__(16) char smem[147456];
  const int tid = threadIdx.x, wave = tid >> 6, lane = tid & 63;
  const int il = lane & 15, ih = lane >> 4;
  const int rs = lane >> 3, cp = lane & 7;
  const int bm = blockIdx.y * 256, bn = blockIdx.x * 192;
  const int wm = wave >> 2, wn = wave & 3;
  const int srow = wave * 8 + rs;

#define R15_STAGE_A(ABUF, T)                                                  \
  _Pragma("unroll") for (int hh = 0; hh < 4; hh++) {                          \
    int row = hh * 64 + srow;                                                 \
    int c = cp ^ (row & 7);                                                   \
    gload16(A + (size_t)(bm + row) * 1024 + (T) * 64 + c * 8,                 \
            smem + (ABUF) * 32768 + hh * 8192 + wave * 1024);                 \
  }
#define R15_STAGE_B(BBUF, T)                                                  \
  _Pragma("unroll") for (int hh = 0; hh < 3; hh++) {                          \
    int row = hh * 64 + srow;                                                 \
    int c = cp ^ (row & 7);                                                   \
    gload16(Bt + (size_t)(bn + row) * 1024 + (T) * 64 + c * 8,                \
            smem + 98304 + (BBUF) * 24576 + hh * 8192 + wave * 1024);         \
  }
// read 2 m-frags of quarter Q into AQ
#define R16_READ_AQ(AQ, Q)                                                    \
  _Pragma("unroll") for (int m = 0; m < 2; m++) {                             \
    int R = wm * 128 + (Q) * 32 + m * 16 + il;                                \
    _Pragma("unroll") for (int ks = 0; ks < 2; ks++)                          \
        AQ[m][ks] = *(const f16x8*)(Abuf + R * 128 +                          \
                                    (((ks * 4 + ih) ^ (R & 7)) * 16));        \
  }
// barrier + 12-MFMA cluster for quarter Q
#define R16_MFMA_Q(AQ, Q)                                                     \
  asm volatile("s_waitcnt lgkmcnt(0)" ::: "memory");                          \
  __builtin_amdgcn_s_barrier();                                               \
  __builtin_amdgcn_s_setprio(1);                                              \
  _Pragma("unroll") for (int m = 0; m < 2; m++)                               \
      _Pragma("unroll") for (int n = 0; n < 3; n++)                           \
          _Pragma("unroll") for (int ks = 0; ks < 2; ks++)                    \
              acc[(Q) * 2 + m][n] =                                           \
                  MFMA16(AQ[m][ks], bf[n][ks], acc[(Q) * 2 + m][n]);          \
  __builtin_amdgcn_s_setprio(0);

  f32x4 acc[8][3] = {};

  // prologue: A0->Ab0, B0->Bb0, A1->Ab1, B1->Bb1; keep A1,B1 in flight
  R15_STAGE_A(0, 0);
  R15_STAGE_B(0, 0);
  R15_STAGE_A(1, 1);
  R15_STAGE_B(1, 1);
  asm volatile("s_waitcnt vmcnt(7)" ::: "memory");
  __builtin_amdgcn_s_barrier();

  int ta = 0, sa = 2;  // Ab index of tile t / of tile t+2 (rot-3)
#pragma unroll 1
  for (int t = 0; t < 16; t++) {
    const char* Abuf = (const char*)smem + ta * 32768;
    const char* Bbuf = (const char*)smem + 98304 + (t & 1) * 24576;
    f16x8 bf[3][2];
    // ---- P0: bf (all n-frags, held for whole tile) + quarter 0; stage A
    {
      f16x8 aq[2][2];
#pragma unroll
      for (int n = 0; n < 3; n++) {
        int C = wn * 48 + n * 16 + il;
#pragma unroll
        for (int ks = 0; ks < 2; ks++)
          bf[n][ks] = *(const f16x8*)(Bbuf + C * 128 + (((ks * 4 + ih) ^ (C & 7)) * 16));
      }
      R16_READ_AQ(aq, 0);
      if (t < 14) { R15_STAGE_A(sa, t + 2); }
      R16_MFMA_Q(aq, 0);
    }
    // ---- P1: quarter 1; stage B (into the buffer P0 just finished reading)
    {
      f16x8 aq[2][2];
      R16_READ_AQ(aq, 1);
      if (t < 14) { R15_STAGE_B(t & 1, t + 2); }
      R16_MFMA_Q(aq, 1);
    }
    // ---- P2: quarter 2
    {
      f16x8 aq[2][2];
      R16_READ_AQ(aq, 2);
      R16_MFMA_Q(aq, 2);
    }
    // ---- P3: quarter 3
    {
      f16x8 aq[2][2];
      R16_READ_AQ(aq, 3);
      R16_MFMA_Q(aq, 3);
    }
    // ---- tile boundary: counted wait for tile t+1's staged data
    if (t <= 13) {
      asm volatile("s_waitcnt vmcnt(7)" ::: "memory");
    } else if (t == 14) {
      asm volatile("s_waitcnt vmcnt(0)" ::: "memory");
    }
    if (t < 15) __builtin_amdgcn_s_barrier();
    ta = (ta == 2) ? 0 : ta + 1;
    sa = (sa == 2) ? 0 : sa + 1;
  }

  // epilogue: identical semantics to gemm16 EPI==0 (acc[8][3], BN=192)
#pragma unroll
  for (int mi = 0; mi < 8; mi++)
#pragma unroll
    for (int ni = 0; ni < 3; ni++) {
      int row0 = bm + wm * 128 + mi * 16 + ih * 4;
      int col = bn + wn * 48 + ni * 16 + il;
      int sec = col >> 10, cc = col & 1023;
      if (sec == 2) {
        int b = row0 >> 11, n = row0 & 2047;
        int bh2 = b * 16 + (cc >> 6), dh = cc & 63;
        union { f16x4 h; uint2 u; } pk;
#pragma unroll
        for (int r = 0; r < 4; r++) pk.h[r] = (_Float16)acc[mi][ni][r];
        *(uint2*)(vt + (size_t)bh2 * 131072 + (size_t)dh * 2048 + n) = pk.u;
      } else {
#pragma unroll
        for (int r = 0; r < 4; r++) {
          int row = row0 + r;
          float v = acc[mi][ni][r];
          if (sec == 0) v *= 0.18033688f;  // fold 0.125*log2(e) into Q
          size_t plane = (size_t)(sec * 32 + (row >> 11) * 16 + (cc >> 6));
          oh[plane * 131072 + (size_t)(row & 2047) * 64 + (cc & 63)] = (_Float16)v;
        }
      }
    }
#undef R15_STAGE_A
#undef R15_STAGE_B
#undef R16_READ_AQ
#undef R16_MFMA_Q
}

// -------------------------- GEMM2 BK=64 (m97 structure, unchanged) ---------
template <int BM, int BN, int EPI>
__global__ __launch_bounds__(256) void gemm16(const _Float16* __restrict__ A,
                                              const _Float16* __restrict__ Bt,
                                              const int K,
                                              _Float16* __restrict__ oh,
                                              _Float16* __restrict__ vt,
                                              float* __restrict__ of,
                                              const float* __restrict__ bias,
                                              const int Nout) {
  constexpr int RF = BM / 32, CF = BN / 32;
  constexpr int SLABS = (BM + BN) / 8;
  __shared__ __align__(16) char smem[(BM + BN) * 128];
  char* As = smem;
  char* Bs = smem + BM * 128;
  const int tid = threadIdx.x, wave = tid >> 6, lane = tid & 63;
  const int il = lane & 15, ih = lane >> 4;
  const int bm = blockIdx.y * BM, bn = blockIdx.x * BN;
  const int wm = wave >> 1, wn = wave & 1;
  const int rs = lane >> 3, cp = lane & 7;

  f32x4 acc[RF][CF] = {};

  for (int k0 = 0; k0 < K; k0 += 64) {
    __syncthreads();
#pragma unroll
    for (int s0 = 0; s0 < SLABS / 4; s0++) {
      int s = wave + s0 * 4;
      int row = s * 8 + rs;
      int c = cp ^ (row & 7);
      if (row < BM)
        gload16(A + (size_t)(bm + row) * K + k0 + c * 8, As + s * 1024);
      else
        gload16(Bt + (size_t)(bn + row - BM) * K + k0 + c * 8, smem + s * 1024);
    }
    __syncthreads();
#pragma unroll
    for (int ks = 0; ks < 2; ks++) {
      f16x8 af[RF], bf[CF];
#pragma unroll
      for (int rf = 0; rf < RF; rf++) {
        int R = wm * (BM / 2) + rf * 16 + il;
        af[rf] = *(const f16x8*)(As + R * 128 + (((ks * 4 + ih) ^ (R & 7)) * 16));
      }
#pragma unroll
      for (int cf = 0; cf < CF; cf++) {
        int C = wn * (BN / 2) + cf * 16 + il;
        bf[cf] = *(const f16x8*)(Bs + C * 128 + (((ks * 4 + ih) ^ (C & 7)) * 16));
      }
#pragma unroll
      for (int rf = 0; rf < RF; rf++)
#pragma unroll
        for (int cf = 0; cf < CF; cf++)
          acc[rf][cf] = MFMA16(af[rf], bf[cf], acc[rf][cf]);
    }
  }

#pragma unroll
  for (int rf = 0; rf < RF; rf++)
#pragma unroll
    for (int cf = 0; cf < CF; cf++) {
      int row0 = bm + wm * (BM / 2) + rf * 16 + ih * 4;
      int col = bn + wn * (BN / 2) + cf * 16 + il;
      if (EPI == 0) {
        int sec = col >> 10, cc = col & 1023;
        if (sec == 2) {
          int b = row0 >> 11, n = row0 & 2047;
          int bh = b * 16 + (cc >> 6), dh = cc & 63;
          union { f16x4 h; uint2 u; } pk;
#pragma unroll
          for (int r = 0; r < 4; r++) pk.h[r] = (_Float16)acc[rf][cf][r];
          *(uint2*)(vt + (size_t)bh * 131072 + (size_t)dh * 2048 + n) = pk.u;
        } else {
#pragma unroll
          for (int r = 0; r < 4; r++) {
            int row = row0 + r;
            float v = acc[rf][cf][r];
            if (sec == 0) v *= 0.18033688f;
            size_t plane = (size_t)(sec * 32 + (row >> 11) * 16 + (cc >> 6));
            oh[plane * 131072 + (size_t)(row & 2047) * 64 + (cc & 63)] = (_Float16)v;
          }
        }
      } else {
#pragma unroll
        for (int r = 0; r < 4; r++)
          of[(size_t)(row0 + r) * Nout + col] = acc[rf][cf][r] + bias[col];
      }
    }
}

// -------------------------- banded flash attention v5 (R11, exact) ---------
// QK^T C-frag at lane (cl,hl): P[k=8g+4hl+i2][q=cl]; packed f16x2 word j of
// group g = k-chunk (4g+2hl+j), j in {0,1}.
// PV B-frag at lane (cl,hl), ks2: needs chunks 8ks2+4hl+{0,1,2,3} of row
// q=cl == {w0,w1} of group G=2ks2+hl from BOTH wave halves.
// Exchange at consume time: lane keeps its own-G words, sends its other-G
// words to the xor-32 partner via __shfl_xor (compiler-modeled cross-lane).
__global__ __launch_bounds__(512) void attn(const _Float16* __restrict__ QKV,
                                            const _Float16* __restrict__ VT,
                                            _Float16* __restrict__ O2) {
  __shared__ __align__(16) char smem[51200];
  const int tid = threadIdx.x, wave = tid >> 6, lane = tid & 63;
  const int qw = wave >> 1, sh = wave & 1;
  const int cl = lane & 31, hl = lane >> 5;
  const int rs = lane >> 3, cp = lane & 7;
  const int q0 = blockIdx.x * 128, bh = blockIdx.y;
  const _Float16* Qg = QKV + (size_t)bh * 131072;
  const _Float16* Kg = QKV + 4194304 + (size_t)bh * 131072;
  const _Float16* Vg = VT + (size_t)bh * 131072;
  const int t0 = (q0 >= 256) ? q0 - 256 : 0;
  const int t1 = (q0 + 384 <= 2048) ? q0 + 384 : 2048;
  const int niter = (t1 - t0) >> 6;

#pragma unroll
  for (int q = 0; q < 2; q++) {
    int s = 2 * wave + q;
    int row = s * 8 + rs;
    int c = cp ^ (row & 7);
    gload16(Qg + (size_t)(q0 + row) * 64 + c * 8, smem + s * 1024);
  }
  {
    char* B0 = smem + 18432;
    int row = wave * 8 + rs;
    int c = cp ^ (row & 7);
    gload16(Kg + (size_t)(t0 + row) * 64 + c * 8, B0 + wave * 1024);
    gload16(Vg + (size_t)row * 2048 + t0 + c * 8, B0 + 8192 + wave * 1024);
  }
  __syncthreads();

  f16x8 bq[4];
  {
    int row = 32 * qw + cl;
#pragma unroll
    for (int ks = 0; ks < 4; ks++)
      bq[ks] = *(const f16x8*)(smem + row * 128 + (((ks * 2 + hl) ^ (row & 7)) * 16));
  }

  f32x16 oacc[2] = {};
  float l_acc = 0.f;
  const int a0 = q0 + 32 * qw;

  for (int i = 0; i < niter; i++) {
    const int kt = t0 + i * 64;
    char* Bc = smem + 18432 + (i & 1) * 16384;
    if (i + 1 < niter) {
      char* Bn = smem + 18432 + ((i + 1) & 1) * 16384;
      int row = wave * 8 + rs;
      int c = cp ^ (row & 7);
      gload16(Kg + (size_t)(kt + 64 + row) * 64 + c * 8, Bn + wave * 1024);
      gload16(Vg + (size_t)row * 2048 + (kt + 64) + c * 8, Bn + 8192 + wave * 1024);
    }
    const int d0 = a0 - (kt + 32 * sh);
    if (d0 < 288 && d0 > -288) {
      char* Ksm = Bc;
      char* Vsm = Bc + 8192;
      f32x16 st = {};
      {
        const int krow = 32 * sh + cl;
        __builtin_amdgcn_s_setprio(1);
#pragma unroll
        for (int ks = 0; ks < 4; ks++) {
          f16x8 ak = *(const f16x8*)(Ksm + krow * 128 + (((ks * 2 + hl) ^ (krow & 7)) * 16));
          st = MFMA32(ak, bq[ks], st);
        }
        __builtin_amdgcn_s_setprio(0);
      }
      unsigned w0a[4], w1a[4];
#pragma unroll
      for (int g = 0; g < 4; g++) {
        float v[4];
#pragma unroll
        for (int i2 = 0; i2 < 4; i2++) {
          float e = __builtin_amdgcn_exp2f(st[4 * g + i2]);
          int kl = 8 * g + 4 * hl + i2;
          if (d0 == 256) e = (cl <= kl) ? e : 0.f;
          else if (d0 == -256) e = (cl >= kl) ? e : 0.f;
          l_acc += e;
          v[i2] = e;
        }
        w0a[g] = pk2(v[0], v[1]);
        w1a[g] = pk2(v[2], v[3]);
      }
#pragma unroll
      for (int ks2 = 0; ks2 < 2; ks2++) {
        unsigned kA0 = w0a[2 * ks2],     kA1 = w1a[2 * ks2];
        unsigned kB0 = w0a[2 * ks2 + 1], kB1 = w1a[2 * ks2 + 1];
        unsigned keep0 = hl ? kB0 : kA0, keep1 = hl ? kB1 : kA1;
        unsigned send0 = hl ? kA0 : kB0, send1 = hl ? kA1 : kB1;
        unsigned r0 = (unsigned)__shfl_xor((int)send0, 32);
        unsigned r1 = (unsigned)__shfl_xor((int)send1, 32);
        union { unsigned u[4]; f16x8 h; } bp;
        bp.u[0] = hl ? r0 : keep0;
        bp.u[1] = hl ? r1 : keep1;
        bp.u[2] = hl ? keep0 : r0;
        bp.u[3] = hl ? keep1 : r1;
        __builtin_amdgcn_s_setprio(1);
#pragma unroll
        for (int db = 0; db < 2; db++) {
          int vrow = 32 * db + cl;
          f16x8 av = *(const f16x8*)(Vsm + vrow * 128 +
                                     (((4 * sh + 2 * ks2 + hl) ^ (vrow & 7)) * 16));
          oacc[db] = MFMA32(av, bp.h, oacc[db]);
        }
        __builtin_amdgcn_s_setprio(0);
      }
    }
    __syncthreads();
  }

  const float lp = l_acc + __shfl_xor(l_acc, 32);
  char* Mq = smem + qw * 8448;
  if (sh == 1) {
#pragma unroll
    for (int db = 0; db < 2; db++)
#pragma unroll
      for (int g = 0; g < 4; g++) {
        int dh0 = 32 * db + 8 * g + 4 * hl;
        f32x2 a = {oacc[db][4 * g + 0], oacc[db][4 * g + 1]};
        f32x2 b = {oacc[db][4 * g + 2], oacc[db][4 * g + 3]};
        *(f32x2*)(Mq + cl * 264 + dh0 * 4) = a;
        *(f32x2*)(Mq + cl * 264 + dh0 * 4 + 8) = b;
      }
    if (hl == 0) *(float*)(smem + 34816 + (qw * 32 + cl) * 4) = lp;
  }
  __syncthreads();
  if (sh == 0) {
    float lo = *(const float*)(smem + 34816 + (qw * 32 + cl) * 4);
    float inv = 1.0f / (lp + lo);
    const int b = bh >> 4, h = bh & 15;
    _Float16* dst = O2 + (size_t)(b * 2048 + a0 + cl) * 1024 + h * 64;
#pragma unroll
    for (int db = 0; db < 2; db++)
#pragma unroll
      for (int g = 0; g < 4; g++) {
        int dh0 = 32 * db + 8 * g + 4 * hl;
        f32x2 a = *(const f32x2*)(Mq + cl * 264 + dh0 * 4);
        f32x2 b2 = *(const f32x2*)(Mq + cl * 264 + dh0 * 4 + 8);
        uint2 pkd = {pk2((oacc[db][4 * g + 0] + a[0]) * inv,
                         (oacc[db][4 * g + 1] + a[1]) * inv),
                     pk2((oacc[db][4 * g + 2] + b2[0]) * inv,
                         (oacc[db][4 * g + 3] + b2[1]) * inv)};
        *(uint2*)(dst + dh0) = pkd;
      }
  }
}

// -------------------------- host launch ------------------------------------

extern "C" void kernel_launch(void* const* d_in, const int* in_sizes, int n_in,
                              void* d_out, int out_size, void* d_ws, size_t ws_size,
                              hipStream_t stream) {
  const float* x = (const float*)d_in[0];
  const float* wqkv = (const float*)d_in[1];
  const float* wproj = (const float*)d_in[2];
  const float* bproj = (const float*)d_in[3];
  float* out = (float*)d_out;
  char* ws = (char*)d_ws;

  _Float16* Xb  = (_Float16*)(ws);                       // 8 MB [4096][1024]
  _Float16* Wqt = (_Float16*)(ws + (size_t)(8  << 20));  // 6 MB [3072][1024]
  _Float16* Wpt = (_Float16*)(ws + (size_t)(14 << 20));  // 2 MB [1024][1024]
  _Float16* QKV = (_Float16*)(ws + (size_t)(16 << 20));  // 16 MB Q,K planes
  _Float16* Vt  = (_Float16*)(ws + (size_t)(40 << 20));  // 8 MB [32][64][2048]
  _Float16* O2  = (_Float16*)(ws);                       // aliases Xb

  prep<<<5120, 256, 0, stream>>>(x, wqkv, wproj, Xb, Wqt, Wpt);
  gemm8p<<<dim3(16, 16), 512, 0, stream>>>(Xb, Wqt, QKV, Vt);
  attn<<<dim3(16, 32), 512, 0, stream>>>(QKV, Vt, O2);
  gemm16<128, 64, 1><<<dim3(16, 32), 256, 0, stream>>>(O2, Wpt, 1024, nullptr,
                                                       nullptr, out, bproj, 1024);
}

// Round 8
// 152.644 us; speedup vs baseline: 1.0237x; 1.0237x over previous
//
#include <hip/hip_runtime.h>
#include <stdint.h>

// ---------------------------------------------------------------------------
// SlidingWindowAttention: B=2, N=2048, C=1024, H=16, Dh=64, window=512 (half=256)
// fp16 MFMA pipeline (4 dispatches) — R17 configuration:
//   prep: x->fp16, W_qkv^T, W_proj^T
//   GEMM1: R15-exact 256x192 2-phase/K-tile counted vmcnt(7), A3/B2 buf
//     (144 KiB), grid 16x16 (100% CU)  [R16 fine 4-phase reverted: +3.1us —
//     5 barriers/tile vs 2; fine phases only pay with bigger per-phase work]
//   GEMM2 NEW (R17): same R15 recipe at 128x128, 512 thr/8 waves (2Mx4N,
//     per-wave 64x32, acc[4][2]), A 3-buf/B 2-buf = 80 KiB -> 2 blocks/CU,
//     single phase/tile {12 reads || stage A -> lgkm+barrier -> stage B ->
//     16-MFMA setprio -> vmcnt(4)+barrier}, grid 8x32=256 blocks (100% CU).
//   attn v5 (R11 exact): 32x32 MFMA, 128q x 8 waves, K/V dbuf, P exchanged
//     in-register via __shfl_xor(.,32), setprio clusters
// Negative results (do NOT retry): R7 1-barrier dbuf BK=32 (+4.6us);
// R9 32x32x16 GEMM MFMA (+2.4us); R5 256q attn tiles (+8us); R10 raw-asm
// v_permlane32_swap (WRONG RESULTS); R12 attn counted-vmcnt 4-buf +
// sched_barrier fences (+7.4us); R13 __launch_bounds__(512,2) on 256² GEMM
// (VGPR cap 128 < acc -> spill); R14 drain0-per-tile (T3 gain IS T4, m218);
// R16 fine 4-phase m-quarter split on gemm1 (+3.1us, barrier overhead).
// Pre-commit: if R17 total >= 153.2, revert GEMM2 to gemm16<128,64,1>.
// ---------------------------------------------------------------------------

typedef _Float16 f16x8 __attribute__((ext_vector_type(8)));
typedef _Float16 f16x4 __attribute__((ext_vector_type(4)));
typedef __fp16   fp16x2n __attribute__((ext_vector_type(2)));
typedef float    f32x2 __attribute__((ext_vector_type(2)));
typedef float    f32x4 __attribute__((ext_vector_type(4)));
typedef float    f32x16 __attribute__((ext_vector_type(16)));

#define MFMA16(a, b, c) __builtin_amdgcn_mfma_f32_16x16x32_f16((a), (b), (c), 0, 0, 0)
#define MFMA32(a, b, c) __builtin_amdgcn_mfma_f32_32x32x16_f16((a), (b), (c), 0, 0, 0)

__device__ __forceinline__ void gload16(const void* g, void* l) {
  __builtin_amdgcn_global_load_lds(
      (const __attribute__((address_space(1))) void*)g,
      (__attribute__((address_space(3))) void*)l, 16, 0, 0);
}

__device__ __forceinline__ unsigned pk2(float a, float b) {
  fp16x2n t = __builtin_amdgcn_cvt_pkrtz(a, b);
  return __builtin_bit_cast(unsigned, t);
}

// -------------------------- fused prep -------------------------------------
__global__ __launch_bounds__(256) void prep(const float* __restrict__ x,
                                            const float* __restrict__ wqkv,
                                            const float* __restrict__ wproj,
                                            _Float16* __restrict__ Xb,
                                            _Float16* __restrict__ Wqt,
                                            _Float16* __restrict__ Wpt) {
  __shared__ float t[64][65];
  const int id = blockIdx.x, tid = threadIdx.x;
  if (id < 4096) {
    int i = (id * 256 + tid) * 4;
    float4 v = *(const float4*)(x + i);
    f16x4 h;
    h[0] = (_Float16)v.x; h[1] = (_Float16)v.y;
    h[2] = (_Float16)v.z; h[3] = (_Float16)v.w;
    *(f16x4*)(Xb + i) = h;
    return;
  }
  const float* in; _Float16* out; int N, bx, by;
  if (id < 4864) { int tt = id - 4096; in = wqkv; out = Wqt; N = 3072; bx = tt % 48; by = tt / 48; }
  else           { int tt = id - 4864; in = wproj; out = Wpt; N = 1024; bx = tt & 15; by = tt >> 4; }
  const int n0 = bx * 64, k0 = by * 64;
  {
    int j = tid & 63;
#pragma unroll
    for (int p = 0; p < 16; p++) {
      int i = p * 4 + (tid >> 6);
      t[i][j] = in[(size_t)(k0 + i) * N + n0 + j];
    }
  }
  __syncthreads();
  {
    int i = tid & 63;
#pragma unroll
    for (int p = 0; p < 16; p++) {
      int j = p * 4 + (tid >> 6);
      out[(size_t)(n0 + j) * 1024 + k0 + i] = (_Float16)t[i][j];
    }
  }
}

// -------------------------- GEMM1: 256x192 2-phase counted (R15 exact) -----
// C = A[4096][1024] @ Bt[3072][1024]^T. 512 thr = 8 waves (2M x 4N); per-wave
// output 128x48 = acc[8][3] f32x4 (96 AGPR). BK=64, 16 K-tiles.
// LDS: A 3 buffers x 32KB (rot-3: A(t) in Ab[t%3]) at smem+0;
//      B 2 buffers x 24KB (B(t) in Bb[t&1]) at smem+98304. Total 144 KiB.
// Rows 128B = 8x16B chunks XOR-swizzled slot = chunk ^ (row&7) (T2).
// Per K-tile t (2 phases, 2 barriers):
//   R0: ds_read af(8) + bf(6, register-held both phases)
//   S0: stage A(t+2); lgkmcnt(0); B1; 24 MFMA (mg0)
//   R1: ds_read ag(8); S1: stage B(t+2) (buffer R0 just read — race-free:
//   all waves' R0 reads completed before B1); 24 MFMA (mg1)
//   vmcnt(7) (t<=13) / vmcnt(0) (t==14) ; B2   — T4, never drain mid-loop
__global__ __launch_bounds__(512) void gemm8p(const _Float16* __restrict__ A,
                                              const _Float16* __restrict__ Bt,
                                              _Float16* __restrict__ oh,
                                              _Float16* __restrict__ vt) {
  __shared__ __align__(16) char smem[147456];
  const int tid = threadIdx.x, wave = tid >> 6, lane = tid & 63;
  const int il = lane & 15, ih = lane >> 4;
  const int rs = lane >> 3, cp = lane & 7;
  const int bm = blockIdx.y * 256, bn = blockIdx.x * 192;
  const int wm = wave >> 2, wn = wave & 3;
  const int srow = wave * 8 + rs;

#define R15_STAGE_A(ABUF, T)                                                  \
  _Pragma("unroll") for (int hh = 0; hh < 4; hh++) {                          \
    int row = hh * 64 + srow;                                                 \
    int c = cp ^ (row & 7);                                                   \
    gload16(A + (size_t)(bm + row) * 1024 + (T) * 64 + c * 8,                 \
            smem + (ABUF) * 32768 + hh * 8192 + wave * 1024);                 \
  }
#define R15_STAGE_B(BBUF, T)                                                  \
  _Pragma("unroll") for (int hh = 0; hh < 3; hh++) {                          \
    int row = hh * 64 + srow;                                                 \
    int c = cp ^ (row & 7);                                                   \
    gload16(Bt + (size_t)(bn + row) * 1024 + (T) * 64 + c * 8,                \
            smem + 98304 + (BBUF) * 24576 + hh * 8192 + wave * 1024);         \
  }

  f32x4 acc[8][3] = {};

  // prologue: A0->Ab0, B0->Bb0, A1->Ab1, B1->Bb1; keep A1,B1 in flight
  R15_STAGE_A(0, 0);
  R15_STAGE_B(0, 0);
  R15_STAGE_A(1, 1);
  R15_STAGE_B(1, 1);
  asm volatile("s_waitcnt vmcnt(7)" ::: "memory");
  __builtin_amdgcn_s_barrier();

  int ta = 0, sa = 2;  // Ab index of tile t / of tile t+2 (rot-3)
#pragma unroll 1
  for (int t = 0; t < 16; t++) {
    const char* Abuf = (const char*)smem + ta * 32768;
    const char* Bbuf = (const char*)smem + 98304 + (t & 1) * 24576;
    f16x8 af[4][2], ag[4][2], bf[3][2];
    // R0: mg0 A-frags + all B-frags
#pragma unroll
    for (int m = 0; m < 4; m++) {
      int R = wm * 128 + m * 16 + il;
#pragma unroll
      for (int ks = 0; ks < 2; ks++)
        af[m][ks] = *(const f16x8*)(Abuf + R * 128 + (((ks * 4 + ih) ^ (R & 7)) * 16));
    }
#pragma unroll
    for (int n = 0; n < 3; n++) {
      int C = wn * 48 + n * 16 + il;
#pragma unroll
      for (int ks = 0; ks < 2; ks++)
        bf[n][ks] = *(const f16x8*)(Bbuf + C * 128 + (((ks * 4 + ih) ^ (C & 7)) * 16));
    }
    // S0: stage A(t+2)
    if (t < 14) { R15_STAGE_A(sa, t + 2); }
    asm volatile("s_waitcnt lgkmcnt(0)" ::: "memory");
    __builtin_amdgcn_s_barrier();
    __builtin_amdgcn_s_setprio(1);
#pragma unroll
    for (int m = 0; m < 4; m++)
#pragma unroll
      for (int n = 0; n < 3; n++)
#pragma unroll
        for (int ks = 0; ks < 2; ks++)
          acc[m][n] = MFMA16(af[m][ks], bf[n][ks], acc[m][n]);
    __builtin_amdgcn_s_setprio(0);
    // R1: mg1 A-frags
#pragma unroll
    for (int m = 0; m < 4; m++) {
      int R = wm * 128 + 64 + m * 16 + il;
#pragma unroll
      for (int ks = 0; ks < 2; ks++)
        ag[m][ks] = *(const f16x8*)(Abuf + R * 128 + (((ks * 4 + ih) ^ (R & 7)) * 16));
    }
    // S1: stage B(t+2) into the buffer R0 just finished reading
    if (t < 14) { R15_STAGE_B(t & 1, t + 2); }
    __builtin_amdgcn_s_setprio(1);
#pragma unroll
    for (int m = 0; m < 4; m++)
#pragma unroll
      for (int n = 0; n < 3; n++)
#pragma unroll
        for (int ks = 0; ks < 2; ks++)
          acc[4 + m][n] = MFMA16(ag[m][ks], bf[n][ks], acc[4 + m][n]);
    __builtin_amdgcn_s_setprio(0);
    if (t <= 13) {
      asm volatile("s_waitcnt vmcnt(7)" ::: "memory");
    } else if (t == 14) {
      asm volatile("s_waitcnt vmcnt(0)" ::: "memory");
    }
    if (t < 15) __builtin_amdgcn_s_barrier();
    ta = (ta == 2) ? 0 : ta + 1;
    sa = (sa == 2) ? 0 : sa + 1;
  }

  // epilogue: QKV/Vt scatter (acc[8][3], BN=192)
#pragma unroll
  for (int mi = 0; mi < 8; mi++)
#pragma unroll
    for (int ni = 0; ni < 3; ni++) {
      int row0 = bm + wm * 128 + mi * 16 + ih * 4;
      int col = bn + wn * 48 + ni * 16 + il;
      int sec = col >> 10, cc = col & 1023;
      if (sec == 2) {
        int b = row0 >> 11, n = row0 & 2047;
        int bh2 = b * 16 + (cc >> 6), dh = cc & 63;
        union { f16x4 h; uint2 u; } pk;
#pragma unroll
        for (int r = 0; r < 4; r++) pk.h[r] = (_Float16)acc[mi][ni][r];
        *(uint2*)(vt + (size_t)bh2 * 131072 + (size_t)dh * 2048 + n) = pk.u;
      } else {
#pragma unroll
        for (int r = 0; r < 4; r++) {
          int row = row0 + r;
          float v = acc[mi][ni][r];
          if (sec == 0) v *= 0.18033688f;  // fold 0.125*log2(e) into Q
          size_t plane = (size_t)(sec * 32 + (row >> 11) * 16 + (cc >> 6));
          oh[plane * 131072 + (size_t)(row & 2047) * 64 + (cc & 63)] = (_Float16)v;
        }
      }
    }
#undef R15_STAGE_A
#undef R15_STAGE_B
}

// -------------------------- GEMM2: 128x128 1-phase counted (R17) -----------
// out = O2[4096][1024] @ Wpt[1024][1024]^T + bias, fp32 out.
// 512 thr = 8 waves (2M x 4N); per-wave 64x32 = acc[4][2] f32x4 (32 reg).
// LDS: A 3 bufs x 16KB at 0 (rot-3); B 2 bufs x 16KB at 49152. 80 KiB ->
// 2 blocks/CU (16 waves/CU). Grid 8x32 = 256 blocks (100% CU).
// Per K-tile t (1 phase): reads af(8)+bf(4); stage A(t+2) [2 gloads];
// lgkmcnt(0)+barrier (certifies all waves' reads of tile t); stage B(t+2)
// into Bb[t&1] (the buffer just read — race-free after barrier); 16-MFMA
// setprio cluster; boundary vmcnt(4) (t<=13; leaves t+2's 4 loads flying,
// waits t+1's) / vmcnt(0) (t==14); barrier.
__global__ __launch_bounds__(512) void gemm2p(const _Float16* __restrict__ A,
                                              const _Float16* __restrict__ Bt,
                                              float* __restrict__ of,
                                              const float* __restrict__ bias) {
  __shared__ __align__(16) char smem[81920];
  const int tid = threadIdx.x, wave = tid >> 6, lane = tid & 63;
  const int il = lane & 15, ih = lane >> 4;
  const int rs = lane >> 3, cp = lane & 7;
  const int bm = blockIdx.y * 128, bn = blockIdx.x * 128;
  const int wm = wave >> 2, wn = wave & 3;
  const int srow = wave * 8 + rs;

#define R17_STAGE_A(ABUF, T)                                                  \
  _Pragma("unroll") for (int hh = 0; hh < 2; hh++) {                          \
    int row = hh * 64 + srow;                                                 \
    int c = cp ^ (row & 7);                                                   \
    gload16(A + (size_t)(bm + row) * 1024 + (T) * 64 + c * 8,                 \
            smem + (ABUF) * 16384 + hh * 8192 + wave * 1024);                 \
  }
#define R17_STAGE_B(BBUF, T)                                                  \
  _Pragma("unroll") for (int hh = 0; hh < 2; hh++) {                          \
    int row = hh * 64 + srow;                                                 \
    int c = cp ^ (row & 7);                                                   \
    gload16(Bt + (size_t)(bn + row) * 1024 + (T) * 64 + c * 8,                \
            smem + 49152 + (BBUF) * 16384 + hh * 8192 + wave * 1024);         \
  }

  f32x4 acc[4][2] = {};

  // prologue: A0->Ab0, B0->Bb0, A1->Ab1, B1->Bb1; keep A1,B1 (4) in flight
  R17_STAGE_A(0, 0);
  R17_STAGE_B(0, 0);
  R17_STAGE_A(1, 1);
  R17_STAGE_B(1, 1);
  asm volatile("s_waitcnt vmcnt(4)" ::: "memory");
  __builtin_amdgcn_s_barrier();

  int ta = 0, sa = 2;  // Ab index of tile t / of tile t+2 (rot-3)
#pragma unroll 1
  for (int t = 0; t < 16; t++) {
    const char* Abuf = (const char*)smem + ta * 16384;
    const char* Bbuf = (const char*)smem + 49152 + (t & 1) * 16384;
    f16x8 af[4][2], bf[2][2];
#pragma unroll
    for (int m = 0; m < 4; m++) {
      int R = wm * 64 + m * 16 + il;
#pragma unroll
      for (int ks = 0; ks < 2; ks++)
        af[m][ks] = *(const f16x8*)(Abuf + R * 128 + (((ks * 4 + ih) ^ (R & 7)) * 16));
    }
#pragma unroll
    for (int n = 0; n < 2; n++) {
      int C = wn * 32 + n * 16 + il;
#pragma unroll
      for (int ks = 0; ks < 2; ks++)
        bf[n][ks] = *(const f16x8*)(Bbuf + C * 128 + (((ks * 4 + ih) ^ (C & 7)) * 16));
    }
    if (t < 14) { R17_STAGE_A(sa, t + 2); }
    asm volatile("s_waitcnt lgkmcnt(0)" ::: "memory");
    __builtin_amdgcn_s_barrier();
    if (t < 14) { R17_STAGE_B(t & 1, t + 2); }
    __builtin_amdgcn_s_setprio(1);
#pragma unroll
    for (int m = 0; m < 4; m++)
#pragma unroll
      for (int n = 0; n < 2; n++)
#pragma unroll
        for (int ks = 0; ks < 2; ks++)
          acc[m][n] = MFMA16(af[m][ks], bf[n][ks], acc[m][n]);
    __builtin_amdgcn_s_setprio(0);
    if (t <= 13) {
      asm volatile("s_waitcnt vmcnt(4)" ::: "memory");
    } else if (t == 14) {
      asm volatile("s_waitcnt vmcnt(0)" ::: "memory");
    }
    if (t < 15) __builtin_amdgcn_s_barrier();
    ta = (ta == 2) ? 0 : ta + 1;
    sa = (sa == 2) ? 0 : sa + 1;
  }

  // epilogue: fp32 out + bias
#pragma unroll
  for (int mi = 0; mi < 4; mi++)
#pragma unroll
    for (int ni = 0; ni < 2; ni++) {
      int row0 = bm + wm * 64 + mi * 16 + ih * 4;
      int col = bn + wn * 32 + ni * 16 + il;
#pragma unroll
      for (int r = 0; r < 4; r++)
        of[(size_t)(row0 + r) * 1024 + col] = acc[mi][ni][r] + bias[col];
    }
#undef R17_STAGE_A
#undef R17_STAGE_B
}

// -------------------------- banded flash attention v5 (R11, exact) ---------
// QK^T C-frag at lane (cl,hl): P[k=8g+4hl+i2][q=cl]; packed f16x2 word j of
// group g = k-chunk (4g+2hl+j), j in {0,1}.
// PV B-frag at lane (cl,hl), ks2: needs chunks 8ks2+4hl+{0,1,2,3} of row
// q=cl == {w0,w1} of group G=2ks2+hl from BOTH wave halves.
// Exchange at consume time: lane keeps its own-G words, sends its other-G
// words to the xor-32 partner via __shfl_xor (compiler-modeled cross-lane).
__global__ __launch_bounds__(512) void attn(const _Float16* __restrict__ QKV,
                                            const _Float16* __restrict__ VT,
                                            _Float16* __restrict__ O2) {
  __shared__ __align__(16) char smem[51200];
  const int tid = threadIdx.x, wave = tid >> 6, lane = tid & 63;
  const int qw = wave >> 1, sh = wave & 1;
  const int cl = lane & 31, hl = lane >> 5;
  const int rs = lane >> 3, cp = lane & 7;
  const int q0 = blockIdx.x * 128, bh = blockIdx.y;
  const _Float16* Qg = QKV + (size_t)bh * 131072;
  const _Float16* Kg = QKV + 4194304 + (size_t)bh * 131072;
  const _Float16* Vg = VT + (size_t)bh * 131072;
  const int t0 = (q0 >= 256) ? q0 - 256 : 0;
  const int t1 = (q0 + 384 <= 2048) ? q0 + 384 : 2048;
  const int niter = (t1 - t0) >> 6;

#pragma unroll
  for (int q = 0; q < 2; q++) {
    int s = 2 * wave + q;
    int row = s * 8 + rs;
    int c = cp ^ (row & 7);
    gload16(Qg + (size_t)(q0 + row) * 64 + c * 8, smem + s * 1024);
  }
  {
    char* B0 = smem + 18432;
    int row = wave * 8 + rs;
    int c = cp ^ (row & 7);
    gload16(Kg + (size_t)(t0 + row) * 64 + c * 8, B0 + wave * 1024);
    gload16(Vg + (size_t)row * 2048 + t0 + c * 8, B0 + 8192 + wave * 1024);
  }
  __syncthreads();

  f16x8 bq[4];
  {
    int row = 32 * qw + cl;
#pragma unroll
    for (int ks = 0; ks < 4; ks++)
      bq[ks] = *(const f16x8*)(smem + row * 128 + (((ks * 2 + hl) ^ (row & 7)) * 16));
  }

  f32x16 oacc[2] = {};
  float l_acc = 0.f;
  const int a0 = q0 + 32 * qw;

  for (int i = 0; i < niter; i++) {
    const int kt = t0 + i * 64;
    char* Bc = smem + 18432 + (i & 1) * 16384;
    if (i + 1 < niter) {
      char* Bn = smem + 18432 + ((i + 1) & 1) * 16384;
      int row = wave * 8 + rs;
      int c = cp ^ (row & 7);
      gload16(Kg + (size_t)(kt + 64 + row) * 64 + c * 8, Bn + wave * 1024);
      gload16(Vg + (size_t)row * 2048 + (kt + 64) + c * 8, Bn + 8192 + wave * 1024);
    }
    const int d0 = a0 - (kt + 32 * sh);
    if (d0 < 288 && d0 > -288) {
      char* Ksm = Bc;
      char* Vsm = Bc + 8192;
      f32x16 st = {};
      {
        const int krow = 32 * sh + cl;
        __builtin_amdgcn_s_setprio(1);
#pragma unroll
        for (int ks = 0; ks < 4; ks++) {
          f16x8 ak = *(const f16x8*)(Ksm + krow * 128 + (((ks * 2 + hl) ^ (krow & 7)) * 16));
          st = MFMA32(ak, bq[ks], st);
        }
        __builtin_amdgcn_s_setprio(0);
      }
      unsigned w0a[4], w1a[4];
#pragma unroll
      for (int g = 0; g < 4; g++) {
        float v[4];
#pragma unroll
        for (int i2 = 0; i2 < 4; i2++) {
          float e = __builtin_amdgcn_exp2f(st[4 * g + i2]);
          int kl = 8 * g + 4 * hl + i2;
          if (d0 == 256) e = (cl <= kl) ? e : 0.f;
          else if (d0 == -256) e = (cl >= kl) ? e : 0.f;
          l_acc += e;
          v[i2] = e;
        }
        w0a[g] = pk2(v[0], v[1]);
        w1a[g] = pk2(v[2], v[3]);
      }
#pragma unroll
      for (int ks2 = 0; ks2 < 2; ks2++) {
        unsigned kA0 = w0a[2 * ks2],     kA1 = w1a[2 * ks2];
        unsigned kB0 = w0a[2 * ks2 + 1], kB1 = w1a[2 * ks2 + 1];
        unsigned keep0 = hl ? kB0 : kA0, keep1 = hl ? kB1 : kA1;
        unsigned send0 = hl ? kA0 : kB0, send1 = hl ? kA1 : kB1;
        unsigned r0 = (unsigned)__shfl_xor((int)send0, 32);
        unsigned r1 = (unsigned)__shfl_xor((int)send1, 32);
        union { unsigned u[4]; f16x8 h; } bp;
        bp.u[0] = hl ? r0 : keep0;
        bp.u[1] = hl ? r1 : keep1;
        bp.u[2] = hl ? keep0 : r0;
        bp.u[3] = hl ? keep1 : r1;
        __builtin_amdgcn_s_setprio(1);
#pragma unroll
        for (int db = 0; db < 2; db++) {
          int vrow = 32 * db + cl;
          f16x8 av = *(const f16x8*)(Vsm + vrow * 128 +
                                     (((4 * sh + 2 * ks2 + hl) ^ (vrow & 7)) * 16));
          oacc[db] = MFMA32(av, bp.h, oacc[db]);
        }
        __builtin_amdgcn_s_setprio(0);
      }
    }
    __syncthreads();
  }

  const float lp = l_acc + __shfl_xor(l_acc, 32);
  char* Mq = smem + qw * 8448;
  if (sh == 1) {
#pragma unroll
    for (int db = 0; db < 2; db++)
#pragma unroll
      for (int g = 0; g < 4; g++) {
        int dh0 = 32 * db + 8 * g + 4 * hl;
        f32x2 a = {oacc[db][4 * g + 0], oacc[db][4 * g + 1]};
        f32x2 b = {oacc[db][4 * g + 2], oacc[db][4 * g + 3]};
        *(f32x2*)(Mq + cl * 264 + dh0 * 4) = a;
        *(f32x2*)(Mq + cl * 264 + dh0 * 4 + 8) = b;
      }
    if (hl == 0) *(float*)(smem + 34816 + (qw * 32 + cl) * 4) = lp;
  }
  __syncthreads();
  if (sh == 0) {
    float lo = *(const float*)(smem + 34816 + (qw * 32 + cl) * 4);
    float inv = 1.0f / (lp + lo);
    const int b = bh >> 4, h = bh & 15;
    _Float16* dst = O2 + (size_t)(b * 2048 + a0 + cl) * 1024 + h * 64;
#pragma unroll
    for (int db = 0; db < 2; db++)
#pragma unroll
      for (int g = 0; g < 4; g++) {
        int dh0 = 32 * db + 8 * g + 4 * hl;
        f32x2 a = *(const f32x2*)(Mq + cl * 264 + dh0 * 4);
        f32x2 b2 = *(const f32x2*)(Mq + cl * 264 + dh0 * 4 + 8);
        uint2 pkd = {pk2((oacc[db][4 * g + 0] + a[0]) * inv,
                         (oacc[db][4 * g + 1] + a[1]) * inv),
                     pk2((oacc[db][4 * g + 2] + b2[0]) * inv,
                         (oacc[db][4 * g + 3] + b2[1]) * inv)};
        *(uint2*)(dst + dh0) = pkd;
      }
  }
}

// -------------------------- host launch ------------------------------------

extern "C" void kernel_launch(void* const* d_in, const int* in_sizes, int n_in,
                              void* d_out, int out_size, void* d_ws, size_t ws_size,
                              hipStream_t stream) {
  const float* x = (const float*)d_in[0];
  const float* wqkv = (const float*)d_in[1];
  const float* wproj = (const float*)d_in[2];
  const float* bproj = (const float*)d_in[3];
  float* out = (float*)d_out;
  char* ws = (char*)d_ws;

  _Float16* Xb  = (_Float16*)(ws);                       // 8 MB [4096][1024]
  _Float16* Wqt = (_Float16*)(ws + (size_t)(8  << 20));  // 6 MB [3072][1024]
  _Float16* Wpt = (_Float16*)(ws + (size_t)(14 << 20));  // 2 MB [1024][1024]
  _Float16* QKV = (_Float16*)(ws + (size_t)(16 << 20));  // 16 MB Q,K planes
  _Float16* Vt  = (_Float16*)(ws + (size_t)(40 << 20));  // 8 MB [32][64][2048]
  _Float16* O2  = (_Float16*)(ws);                       // aliases Xb

  prep<<<5120, 256, 0, stream>>>(x, wqkv, wproj, Xb, Wqt, Wpt);
  gemm8p<<<dim3(16, 16), 512, 0, stream>>>(Xb, Wqt, QKV, Vt);
  attn<<<dim3(16, 32), 512, 0, stream>>>(QKV, Vt, O2);
  gemm2p<<<dim3(8, 32), 512, 0, stream>>>(O2, Wpt, out, bproj);
}